// Round 10
// baseline (219.797 us; speedup 1.0000x reference)
//
#include <hip/hip_runtime.h>

#define N_NODES 50000
#define N_EDGES 800000
#define WT_PAD 136      // LDS row stride in shorts (272 B: 16B-aligned, 2-way-free banks)
#define DUMMY N_NODES   // per-plane row 50000 is zeroed; CSR padding points here
#define SLOT_LOG 6      // 64 slots per node (max degree ~45 for Poisson(16))
#define PLANE_SH 1600064  // shorts per channel-quarter plane (50001 rows x 32ch, padded)

#define NB2 782         // buckets of 64 nodes (== gemm 64-row tiles)
#define CAP 28          // edges per (block,bucket) cell; mean 5.24, P(ovfl)~7e-8/run
#define EPB 4096        // edges per partition block
#define PART_BLOCKS 196 // ceil(800000/4096)
#define AGG_BLKS 782    // 64 nodes/block per plane dispatch (4 lanes/node)

typedef __attribute__((ext_vector_type(8))) short short8;   // 8 bf16 = one MFMA A/B frag
typedef __attribute__((ext_vector_type(4))) float floatx4;  // MFMA C/D frag / NT stores

__device__ __forceinline__ short f2bf(float f) {  // RNE float->bf16
    union { float f; unsigned u; } v; v.f = f;
    unsigned r = v.u + 0x7fff + ((v.u >> 16) & 1);
    return (short)(r >> 16);
}
__device__ __forceinline__ float bflo(unsigned u) {
    union { unsigned u; float f; } v; v.u = u << 16; return v.f;
}
__device__ __forceinline__ float bfhi(unsigned u) {
    union { unsigned u; float f; } v; v.u = u & 0xffff0000u; return v.f;
}

// -------- dispatch 1: prep (blocks 0..65) + fixed-cap 2D partition (all 196) ----------
// bd2[blk][bucket][CAP]: each block owns its cells -> no global atomics, no pre-zeroing.

__global__ __launch_bounds__(256) void partition_prep(const int* __restrict__ ei,
                                                      const float* __restrict__ W1,
                                                      const float* __restrict__ W2,
                                                      const float* __restrict__ W3,
                                                      const float* __restrict__ b2,
                                                      const float* __restrict__ b3,
                                                      unsigned short* __restrict__ Wt1,
                                                      unsigned short* __restrict__ Wt23,
                                                      float* __restrict__ b23,
                                                      int* __restrict__ cnt2d,
                                                      unsigned* __restrict__ bd2,
                                                      unsigned short* __restrict__ g1) {
    int tid = threadIdx.x, blk = blockIdx.x;
    if (blk < 66) {                                  // prep slice
        int i = blk * 256 + tid;
        if (i < 128 * 128) {
            int n = i >> 7, k = i & 127;
            Wt1[i] = (unsigned short)f2bf(W1[k * 128 + n]);
            float w = (n < 64) ? W2[k * 64 + n] : W3[k * 64 + (n - 64)];
            Wt23[i] = (unsigned short)f2bf(w);
        } else if (i < 128 * 128 + 128) {
            int k2 = i - 128 * 128;
            b23[k2] = (k2 < 64) ? b2[k2] : b3[k2 - 64];
        } else if (i < 128 * 128 + 192) {
            int j = i - (128 * 128 + 128);           // 0..63: zero 4 plane dummy rows
            unsigned* p = (unsigned*)(g1 + (size_t)(j >> 4) * PLANE_SH + (size_t)DUMMY * 32);
            p[j & 15] = 0;
        }
    }
    __shared__ int cur[NB2];
    for (int i = tid; i < NB2; i += 256) cur[i] = 0;
    __syncthreads();
    int e0 = blk * EPB;
    int tot = N_EDGES - e0; if (tot > EPB) tot = EPB;
    for (int j = tid; j < tot; j += 256) {
        int e = e0 + j;
        int src = ei[e];
        int d = ei[N_EDGES + e];
        int b = d >> 6;
        int pos = atomicAdd(&cur[b], 1);             // LDS cursor
        if (pos < CAP)
            bd2[((size_t)blk * NB2 + b) * CAP + pos] = ((unsigned)d << 16) | (unsigned)src;
    }
    __syncthreads();
    for (int b = tid; b < NB2; b += 256) {
        int c = cur[b]; if (c > CAP) c = CAP;
        cnt2d[blk * NB2 + b] = c;
    }
}

// -------- dispatch 2: fused CSR build (64-node bucket) + MFMA gemm (same 64 rows) ------
// Round-8 drain (per-thread serial over its partition-block cell; proven best).
// ctr[] stays in LDS across both phases; gemm writes g in 4 channel-quarter planes.

template <bool A_BF16>
__global__ __launch_bounds__(256) void csr_gemm(const unsigned* __restrict__ bd2,
                                                const int* __restrict__ cnt2d,
                                                const void* __restrict__ Ain,
                                                const unsigned short* __restrict__ Wt,
                                                int* __restrict__ counts,
                                                unsigned short* __restrict__ sorted_src,
                                                unsigned short* __restrict__ g) {
    __shared__ unsigned short lds[128 * WT_PAD];     // 34816 B; csr slots use first 8 KB
    __shared__ int ctr[64];                          // survives into gemm phase
    int tid = threadIdx.x, b = blockIdx.x;
    uint4* slots4 = (uint4*)lds;                     // 64 rows x 64 shorts = 512 uint4
    unsigned short* slots = lds;

    if (tid < 64) ctr[tid] = 0;
    const unsigned dpat = ((unsigned)DUMMY) | (((unsigned)DUMMY) << 16);
    for (int i = tid; i < 512; i += 256) slots4[i] = make_uint4(dpat, dpat, dpat, dpat);
    __syncthreads();

    if (tid < PART_BLOCKS) {                         // thread t drains partition-block t's cell
        int cell = tid * NB2 + b;
        int c = cnt2d[cell];
        const unsigned* cp = bd2 + (size_t)cell * CAP;
        for (int j = 0; j < c; ++j) {
            unsigned w = cp[j];
            int dl = (int)((w >> 16) & 63);
            int r = atomicAdd(&ctr[dl], 1);          // LDS atomic
            if (r < 64) slots[(dl << 6) + r] = (unsigned short)(w & 0xffffu);
        }
    }
    __syncthreads();

    int node0 = b << 6;
    if (tid < 64 && node0 + tid < N_NODES) counts[node0 + tid] = ctr[tid];
    uint4* gs = (uint4*)(sorted_src + ((size_t)node0 << SLOT_LOG));
    for (int k = tid; k < 512; k += 256) {           // coalesced slot flush
        int row = k >> 3;
        if (node0 + row < N_NODES) gs[k] = slots4[k];
    }
    __syncthreads();                                 // slots flushed; lds reused for Wt

    // ---- gemm phase: g_q[n] = bf16( rsqrt(ctr[n]+1) * (A @ W)[n] ), planar output ----
    int wave = tid >> 6, lane = tid & 63;
    int quad = lane >> 4, ln = lane & 15;
    {   // stage Wt (16384 shorts)
        int r = tid >> 1, h = tid & 1;
        const int4* src = (const int4*)(Wt + r * 128 + h * 64);
#pragma unroll
        for (int i = 0; i < 8; ++i)
            *(int4*)&lds[r * WT_PAD + h * 64 + i * 8] = src[i];
    }
    int row_base = node0 + wave * 16;
    int arow = row_base + ln;
    bool ok = arow < N_NODES;
    short8 afrag[4];
    if (A_BF16) {
        const unsigned short* A = (const unsigned short*)Ain;
#pragma unroll
        for (int kk = 0; kk < 4; ++kk) {
            short8 v = {};
            if (ok) v = *(const short8*)(A + arow * 128 + kk * 32 + quad * 8);
            afrag[kk] = v;
        }
    } else {
        const float* A = (const float*)Ain;
#pragma unroll
        for (int kk = 0; kk < 4; ++kk) {
            short8 v = {};
            if (ok) {
                const floatx4* p = (const floatx4*)(A + arow * 128 + kk * 32 + quad * 8);
                floatx4 fa = p[0], fb = p[1];
                v[0] = f2bf(fa.x); v[1] = f2bf(fa.y); v[2] = f2bf(fa.z); v[3] = f2bf(fa.w);
                v[4] = f2bf(fb.x); v[5] = f2bf(fb.y); v[6] = f2bf(fb.z); v[7] = f2bf(fb.w);
            }
            afrag[kk] = v;
        }
    }
    __syncthreads();

    floatx4 acc[8] = {};
#pragma unroll
    for (int n0 = 0; n0 < 8; ++n0) {
#pragma unroll
        for (int kk = 0; kk < 4; ++kk) {
            short8 bb = *(const short8*)&lds[(n0 * 16 + ln) * WT_PAD + kk * 32 + quad * 8];
            acc[n0] = __builtin_amdgcn_mfma_f32_16x16x32_bf16(afrag[kk], bb, acc[n0], 0, 0, 0);
        }
    }

    __syncthreads();  // done with Wt; reuse LDS for epilogue transpose
    unsigned short* st = &lds[wave * 16 * WT_PAD];
    float dv[4];
#pragma unroll
    for (int r = 0; r < 4; ++r) {
        int node = row_base + quad * 4 + r;
        dv[r] = (node < N_NODES) ? rsqrtf((float)(ctr[wave * 16 + quad * 4 + r] + 1)) : 0.f;
    }
#pragma unroll
    for (int n0 = 0; n0 < 8; ++n0)
#pragma unroll
        for (int r = 0; r < 4; ++r)
            st[(quad * 4 + r) * WT_PAD + n0 * 16 + ln] =
                (unsigned short)f2bf(acc[n0][r] * dv[r]);
    __syncthreads();

    int q = ln >> 2, cq = ln & 3;                    // plane + within-plane col group
#pragma unroll
    for (int i = 0; i < 4; ++i) {
        int row = i * 4 + quad;
        int node = row_base + row;
        short8 v = *(const short8*)&st[row * WT_PAD + ln * 8];
        if (node < N_NODES)
            *(short8*)(g + (size_t)q * PLANE_SH + node * 32 + cq * 8) = v;
    }
}

// -------- dispatch 6: standalone MFMA gemm (layer 2+3), planar output ------------------

__global__ __launch_bounds__(256) void gemm_mfma(const unsigned short* __restrict__ A,
                                                 const unsigned short* __restrict__ Wt,
                                                 const int* __restrict__ degs,
                                                 unsigned short* __restrict__ g) {
    __shared__ unsigned short lds[128 * WT_PAD];  // 34816 B; reused by epilogue
    int tid = threadIdx.x;
    int wave = tid >> 6, lane = tid & 63;
    int quad = lane >> 4, ln = lane & 15;

    {   // stage Wt (16384 shorts)
        int r = tid >> 1, h = tid & 1;
        const int4* src = (const int4*)(Wt + r * 128 + h * 64);
#pragma unroll
        for (int i = 0; i < 8; ++i)
            *(int4*)&lds[r * WT_PAD + h * 64 + i * 8] = src[i];
    }

    int row_base = blockIdx.x * 64 + wave * 16;
    int arow = row_base + ln;
    bool ok = arow < N_NODES;
    short8 afrag[4];
#pragma unroll
    for (int kk = 0; kk < 4; ++kk) {
        short8 v = {};
        if (ok) v = *(const short8*)(A + arow * 128 + kk * 32 + quad * 8);
        afrag[kk] = v;
    }
    __syncthreads();

    floatx4 acc[8] = {};
#pragma unroll
    for (int n0 = 0; n0 < 8; ++n0) {
#pragma unroll
        for (int kk = 0; kk < 4; ++kk) {
            short8 b = *(const short8*)&lds[(n0 * 16 + ln) * WT_PAD + kk * 32 + quad * 8];
            acc[n0] = __builtin_amdgcn_mfma_f32_16x16x32_bf16(afrag[kk], b, acc[n0], 0, 0, 0);
        }
    }

    __syncthreads();  // done with Wt; reuse LDS for epilogue transpose
    unsigned short* st = &lds[wave * 16 * WT_PAD];
    float dv[4];
#pragma unroll
    for (int r = 0; r < 4; ++r) {
        int node = row_base + quad * 4 + r;
        dv[r] = (node < N_NODES) ? rsqrtf((float)(degs[node] + 1)) : 0.f;
    }
#pragma unroll
    for (int n0 = 0; n0 < 8; ++n0)
#pragma unroll
        for (int r = 0; r < 4; ++r)
            st[(quad * 4 + r) * WT_PAD + n0 * 16 + ln] =
                (unsigned short)f2bf(acc[n0][r] * dv[r]);
    __syncthreads();

    int q = ln >> 2, cq = ln & 3;
#pragma unroll
    for (int i = 0; i < 4; ++i) {
        int row = i * 4 + quad;
        int node = row_base + row;
        short8 v = *(const short8*)&st[row * WT_PAD + ln * 8];
        if (node < N_NODES)
            *(short8*)(g + (size_t)q * PLANE_SH + node * 32 + cq * 8) = v;
    }
}

// -------- dispatches 3..5+ / 7..10: per-plane aggregation (L2-resident gather) ---------
// One dispatch per 3.2 MB channel-quarter plane: the random gather's working set fits a
// single XCD L2 (4 MB), so steady-state gathers are L2 hits instead of L3/fabric misses.
// 4 lanes/node x 4 planes == 16 lanes/node total: identical per-lane load/VALU counts.

template <int MODE>  // 0: bf16 hidden [N][128]; 1: fp32 split out (x1 | x2)
__global__ __launch_bounds__(256) void agg_plane(const unsigned short* __restrict__ g,
                                                 const int* __restrict__ degs,
                                                 const unsigned short* __restrict__ srcs,
                                                 const float* __restrict__ bias,
                                                 void* __restrict__ outp, int plane) {
    int n = blockIdx.x * 64 + (threadIdx.x >> 2);
    if (n >= N_NODES) return;
    int c4 = threadIdx.x & 3;                        // uint4 index within the 64 B slice
    const uint4* grow = (const uint4*)(g + (size_t)plane * PLANE_SH);  // 4 uint4 per row
    uint4 u = grow[n * 4 + c4];                      // self-loop term
    float a0 = bflo(u.x), a1 = bfhi(u.x), a2 = bflo(u.y), a3 = bfhi(u.y);
    float a4 = bflo(u.z), a5 = bfhi(u.z), a6 = bflo(u.w), a7 = bfhi(u.w);
    float c0 = 0.f, c1 = 0.f, c2 = 0.f, c3 = 0.f, c5 = 0.f, c6 = 0.f, c7 = 0.f, c8 = 0.f;
    int deg = degs[n];
    int degc = deg > 64 ? 64 : deg;
    int beg = n << SLOT_LOG;
    int pend = beg + ((degc + 3) & ~3);              // pad slots hold DUMMY (zero row)
    int e = beg;
    for (; e + 8 <= pend; e += 8) {
        ushort4 sa = *(const ushort4*)&srcs[e];
        ushort4 sb = *(const ushort4*)&srcs[e + 4];
        uint4 v0 = grow[sa.x * 4 + c4];
        uint4 v1 = grow[sa.y * 4 + c4];
        uint4 v2 = grow[sa.z * 4 + c4];
        uint4 v3 = grow[sa.w * 4 + c4];
        uint4 v4 = grow[sb.x * 4 + c4];
        uint4 v5 = grow[sb.y * 4 + c4];
        uint4 v6 = grow[sb.z * 4 + c4];
        uint4 v7 = grow[sb.w * 4 + c4];
        a0 += bflo(v0.x); a1 += bfhi(v0.x); a2 += bflo(v0.y); a3 += bfhi(v0.y);
        a4 += bflo(v0.z); a5 += bfhi(v0.z); a6 += bflo(v0.w); a7 += bfhi(v0.w);
        c0 += bflo(v1.x); c1 += bfhi(v1.x); c2 += bflo(v1.y); c3 += bfhi(v1.y);
        c5 += bflo(v1.z); c6 += bfhi(v1.z); c7 += bflo(v1.w); c8 += bfhi(v1.w);
        a0 += bflo(v2.x); a1 += bfhi(v2.x); a2 += bflo(v2.y); a3 += bfhi(v2.y);
        a4 += bflo(v2.z); a5 += bfhi(v2.z); a6 += bflo(v2.w); a7 += bfhi(v2.w);
        c0 += bflo(v3.x); c1 += bfhi(v3.x); c2 += bflo(v3.y); c3 += bfhi(v3.y);
        c5 += bflo(v3.z); c6 += bfhi(v3.z); c7 += bflo(v3.w); c8 += bfhi(v3.w);
        a0 += bflo(v4.x); a1 += bfhi(v4.x); a2 += bflo(v4.y); a3 += bfhi(v4.y);
        a4 += bflo(v4.z); a5 += bfhi(v4.z); a6 += bflo(v4.w); a7 += bfhi(v4.w);
        c0 += bflo(v5.x); c1 += bfhi(v5.x); c2 += bflo(v5.y); c3 += bfhi(v5.y);
        c5 += bflo(v5.z); c6 += bfhi(v5.z); c7 += bflo(v5.w); c8 += bfhi(v5.w);
        a0 += bflo(v6.x); a1 += bfhi(v6.x); a2 += bflo(v6.y); a3 += bfhi(v6.y);
        a4 += bflo(v6.z); a5 += bfhi(v6.z); a6 += bflo(v6.w); a7 += bfhi(v6.w);
        c0 += bflo(v7.x); c1 += bfhi(v7.x); c2 += bflo(v7.y); c3 += bfhi(v7.y);
        c5 += bflo(v7.z); c6 += bfhi(v7.z); c7 += bflo(v7.w); c8 += bfhi(v7.w);
    }
    if (e < pend) {  // exactly one 4-wide chunk (pend-beg is a multiple of 4)
        ushort4 sa = *(const ushort4*)&srcs[e];
        uint4 v0 = grow[sa.x * 4 + c4];
        uint4 v1 = grow[sa.y * 4 + c4];
        uint4 v2 = grow[sa.z * 4 + c4];
        uint4 v3 = grow[sa.w * 4 + c4];
        a0 += bflo(v0.x); a1 += bfhi(v0.x); a2 += bflo(v0.y); a3 += bfhi(v0.y);
        a4 += bflo(v0.z); a5 += bfhi(v0.z); a6 += bflo(v0.w); a7 += bfhi(v0.w);
        c0 += bflo(v1.x); c1 += bfhi(v1.x); c2 += bflo(v1.y); c3 += bfhi(v1.y);
        c5 += bflo(v1.z); c6 += bfhi(v1.z); c7 += bflo(v1.w); c8 += bfhi(v1.w);
        a0 += bflo(v2.x); a1 += bfhi(v2.x); a2 += bflo(v2.y); a3 += bfhi(v2.y);
        a4 += bflo(v2.z); a5 += bfhi(v2.z); a6 += bflo(v2.w); a7 += bfhi(v2.w);
        c0 += bflo(v3.x); c1 += bfhi(v3.x); c2 += bflo(v3.y); c3 += bfhi(v3.y);
        c5 += bflo(v3.z); c6 += bfhi(v3.z); c7 += bflo(v3.w); c8 += bfhi(v3.w);
    }
    a0 += c0; a1 += c1; a2 += c2; a3 += c3; a4 += c5; a5 += c6; a6 += c7; a7 += c8;
    float d = rsqrtf((float)(deg + 1));
    float4 bv0 = ((const float4*)bias)[plane * 8 + c4 * 2];
    float4 bv1 = ((const float4*)bias)[plane * 8 + c4 * 2 + 1];
    float o0 = fmaxf(d * a0 + bv0.x, 0.f);
    float o1 = fmaxf(d * a1 + bv0.y, 0.f);
    float o2 = fmaxf(d * a2 + bv0.z, 0.f);
    float o3 = fmaxf(d * a3 + bv0.w, 0.f);
    float o4 = fmaxf(d * a4 + bv1.x, 0.f);
    float o5 = fmaxf(d * a5 + bv1.y, 0.f);
    float o6 = fmaxf(d * a6 + bv1.z, 0.f);
    float o7 = fmaxf(d * a7 + bv1.w, 0.f);
    if (MODE == 0) {
        uint4 w;
        w.x = ((unsigned)(unsigned short)f2bf(o0)) | (((unsigned)(unsigned short)f2bf(o1)) << 16);
        w.y = ((unsigned)(unsigned short)f2bf(o2)) | (((unsigned)(unsigned short)f2bf(o3)) << 16);
        w.z = ((unsigned)(unsigned short)f2bf(o4)) | (((unsigned)(unsigned short)f2bf(o5)) << 16);
        w.w = ((unsigned)(unsigned short)f2bf(o6)) | (((unsigned)(unsigned short)f2bf(o7)) << 16);
        ((uint4*)outp)[n * 16 + plane * 4 + c4] = w;  // hidden stays interleaved [N][128]
    } else {
        // planes 0-1 -> x1 (fp32 [N][64]); planes 2-3 -> x2
        int hh = plane >> 1, cb = (plane & 1) * 32 + c4 * 8;
        float* out = (float*)outp + (size_t)hh * N_NODES * 64 + (size_t)n * 64 + cb;
        floatx4 w0; w0.x = o0; w0.y = o1; w0.z = o2; w0.w = o3;
        floatx4 w1; w1.x = o4; w1.y = o5; w1.z = o6; w1.w = o7;
        __builtin_nontemporal_store(w0, (floatx4*)out);
        __builtin_nontemporal_store(w1, (floatx4*)out + 1);
    }
}

// ---------------- launch (11 dispatches; launches proven cheap in round 8) -------------

extern "C" void kernel_launch(void* const* d_in, const int* in_sizes, int n_in,
                              void* d_out, int out_size, void* d_ws, size_t ws_size,
                              hipStream_t stream) {
    const float* x  = (const float*)d_in[0];
    const int*   ei = (const int*)d_in[1];   // [2, E] int32
    const float* W1 = (const float*)d_in[2];
    const float* b1 = (const float*)d_in[3];
    const float* W2 = (const float*)d_in[4];
    const float* b2 = (const float*)d_in[5];
    const float* W3 = (const float*)d_in[6];
    const float* b3 = (const float*)d_in[7];
    float* out = (float*)d_out;

    // Workspace layout. g1 = 4 planes x 3,200,128 B = 12,800,512 B; bd2 (17.17 MB, dead
    // after csr_gemm) overlays hidden. Total 37,248,128 B (proven bound 38,490,112).
    char* w = (char*)d_ws;
    int*            counts     = (int*)(w + 0);                   // 200,000 B (true degree)
    int*            cnt2d      = (int*)(w + 200704);              // 613,088 B (196*782 ints)
    unsigned short* Wt1        = (unsigned short*)(w + 815104);   // 32,768 B
    unsigned short* Wt23       = (unsigned short*)(w + 847872);   // 32,768 B
    float*          b23        = (float*)(w + 880640);            // 512 B
    unsigned short* sorted_src = (unsigned short*)(w + 881152);   // 6,400,000 B
    unsigned short* g1         = (unsigned short*)(w + 7281152);  // 12,800,512 B (4 planes)
    unsigned*       bd2        = (unsigned*)(w + 20081664);       // 17,166,464 B (196*782*28*4)
    unsigned short* hidden     = (unsigned short*)(w + 20081664); // 12,800,000 B (overlays bd2)

    partition_prep<<<PART_BLOCKS, 256, 0, stream>>>(ei, W1, W2, W3, b2, b3, Wt1, Wt23, b23,
                                                    cnt2d, bd2, g1);

    // layer 1 (fused CSR + gemm): g1 planes = bf16(dinv * (x @ W1)); hidden via 4 plane aggs
    csr_gemm<false><<<NB2, 256, 0, stream>>>(bd2, cnt2d, x, Wt1, counts, sorted_src, g1);
    for (int q = 0; q < 4; ++q)
        agg_plane<0><<<AGG_BLKS, 256, 0, stream>>>(g1, counts, sorted_src, b1, hidden, q);

    // layers 2+3 fused: g1 planes = bf16(dinv * (hidden @ [W2|W3])); out via 4 plane aggs
    gemm_mfma<<<NB2, 256, 0, stream>>>(hidden, Wt23, counts, g1);
    for (int q = 0; q < 4; ++q)
        agg_plane<1><<<AGG_BLKS, 256, 0, stream>>>(g1, counts, sorted_src, b23, out, q);
}

// Round 11
// 191.035 us; speedup vs baseline: 1.1506x; 1.1506x over previous
//
#include <hip/hip_runtime.h>

#define N_NODES 50000
#define N_EDGES 800000
#define WT_PAD 136      // LDS row stride in shorts (272 B: 16B-aligned, 2-way-free banks)
#define DUMMY N_NODES   // g row 50000 is zeroed; CSR padding points here
#define SLOT_LOG 6      // 64 slots per node (max degree ~45 for Poisson(16))
#define AGG_BLKS 3125   // 50000/16 nodes per block (16 lanes/node, single phase)

#define NB2 782         // buckets of 64 nodes (== gemm 64-row tiles)
#define CAP 28          // edges per (block,bucket) cell; mean 5.24, P(ovfl)~7e-8/run
#define EPB 4096        // edges per partition block
#define PART_BLOCKS 196 // ceil(800000/4096)

typedef __attribute__((ext_vector_type(8))) short short8;   // 8 bf16 = one MFMA A/B frag
typedef __attribute__((ext_vector_type(4))) float floatx4;  // MFMA C/D frag / NT stores

__device__ __forceinline__ short f2bf(float f) {  // RNE float->bf16
    union { float f; unsigned u; } v; v.f = f;
    unsigned r = v.u + 0x7fff + ((v.u >> 16) & 1);
    return (short)(r >> 16);
}
__device__ __forceinline__ float bflo(unsigned u) {
    union { unsigned u; float f; } v; v.u = u << 16; return v.f;
}
__device__ __forceinline__ float bfhi(unsigned u) {
    union { unsigned u; float f; } v; v.u = u & 0xffff0000u; return v.f;
}

// -------- dispatch 1: prep (blocks 0..65) + fixed-cap 2D partition (all 196) ----------
// bd2[blk][bucket][CAP]: each block owns its cells -> no global atomics, no pre-zeroing.

__global__ __launch_bounds__(256) void partition_prep(const int* __restrict__ ei,
                                                      const float* __restrict__ W1,
                                                      const float* __restrict__ W2,
                                                      const float* __restrict__ W3,
                                                      const float* __restrict__ b2,
                                                      const float* __restrict__ b3,
                                                      unsigned short* __restrict__ Wt1,
                                                      unsigned short* __restrict__ Wt23,
                                                      float* __restrict__ b23,
                                                      int* __restrict__ cnt2d,
                                                      unsigned* __restrict__ bd2,
                                                      unsigned int* __restrict__ gdummy) {
    int tid = threadIdx.x, blk = blockIdx.x;
    if (blk < 66) {                                  // prep slice
        int i = blk * 256 + tid;
        if (i < 128 * 128) {
            int n = i >> 7, k = i & 127;
            Wt1[i] = (unsigned short)f2bf(W1[k * 128 + n]);
            float w = (n < 64) ? W2[k * 64 + n] : W3[k * 64 + (n - 64)];
            Wt23[i] = (unsigned short)f2bf(w);
        } else if (i < 128 * 128 + 128) {
            int k2 = i - 128 * 128;
            b23[k2] = (k2 < 64) ? b2[k2] : b3[k2 - 64];
        } else if (i < 128 * 128 + 192) {
            gdummy[i - (128 * 128 + 128)] = 0;       // 64 uints = 128 bf16 zeros
        }
    }
    __shared__ int cur[NB2];
    for (int i = tid; i < NB2; i += 256) cur[i] = 0;
    __syncthreads();
    int e0 = blk * EPB;
    int tot = N_EDGES - e0; if (tot > EPB) tot = EPB;
    for (int j = tid; j < tot; j += 256) {
        int e = e0 + j;
        int src = ei[e];
        int d = ei[N_EDGES + e];
        int b = d >> 6;
        int pos = atomicAdd(&cur[b], 1);             // LDS cursor
        if (pos < CAP)
            bd2[((size_t)blk * NB2 + b) * CAP + pos] = ((unsigned)d << 16) | (unsigned)src;
    }
    __syncthreads();
    for (int b = tid; b < NB2; b += 256) {
        int c = cur[b]; if (c > CAP) c = CAP;
        cnt2d[blk * NB2 + b] = c;
    }
}

// -------- dispatch 2: fused CSR build (64-node bucket) + MFMA gemm (same 64 rows) ------
// Round-8 drain (per-thread serial over its partition-block cell; proven best).

template <bool A_BF16>
__global__ __launch_bounds__(256) void csr_gemm(const unsigned* __restrict__ bd2,
                                                const int* __restrict__ cnt2d,
                                                const void* __restrict__ Ain,
                                                const unsigned short* __restrict__ Wt,
                                                int* __restrict__ counts,
                                                unsigned short* __restrict__ sorted_src,
                                                unsigned short* __restrict__ g) {
    __shared__ unsigned short lds[128 * WT_PAD];     // 34816 B; csr slots use first 8 KB
    __shared__ int ctr[64];                          // survives into gemm phase
    int tid = threadIdx.x, b = blockIdx.x;
    uint4* slots4 = (uint4*)lds;                     // 64 rows x 64 shorts = 512 uint4
    unsigned short* slots = lds;

    if (tid < 64) ctr[tid] = 0;
    const unsigned dpat = ((unsigned)DUMMY) | (((unsigned)DUMMY) << 16);
    for (int i = tid; i < 512; i += 256) slots4[i] = make_uint4(dpat, dpat, dpat, dpat);
    __syncthreads();

    if (tid < PART_BLOCKS) {                         // thread t drains partition-block t's cell
        int cell = tid * NB2 + b;
        int c = cnt2d[cell];
        const unsigned* cp = bd2 + (size_t)cell * CAP;
        for (int j = 0; j < c; ++j) {
            unsigned w = cp[j];
            int dl = (int)((w >> 16) & 63);
            int r = atomicAdd(&ctr[dl], 1);          // LDS atomic
            if (r < 64) slots[(dl << 6) + r] = (unsigned short)(w & 0xffffu);
        }
    }
    __syncthreads();

    int node0 = b << 6;
    if (tid < 64 && node0 + tid < N_NODES) counts[node0 + tid] = ctr[tid];
    uint4* gs = (uint4*)(sorted_src + ((size_t)node0 << SLOT_LOG));
    for (int k = tid; k < 512; k += 256) {           // coalesced slot flush
        int row = k >> 3;
        if (node0 + row < N_NODES) gs[k] = slots4[k];
    }
    __syncthreads();                                 // slots flushed; lds reused for Wt

    // ---- gemm phase: g[n] = bf16( rsqrt(ctr[n]+1) * (A @ W)[n] ) ----
    int wave = tid >> 6, lane = tid & 63;
    int quad = lane >> 4, ln = lane & 15;
    {   // stage Wt (16384 shorts)
        int r = tid >> 1, h = tid & 1;
        const int4* src = (const int4*)(Wt + r * 128 + h * 64);
#pragma unroll
        for (int i = 0; i < 8; ++i)
            *(int4*)&lds[r * WT_PAD + h * 64 + i * 8] = src[i];
    }
    int row_base = node0 + wave * 16;
    int arow = row_base + ln;
    bool ok = arow < N_NODES;
    short8 afrag[4];
    if (A_BF16) {
        const unsigned short* A = (const unsigned short*)Ain;
#pragma unroll
        for (int kk = 0; kk < 4; ++kk) {
            short8 v = {};
            if (ok) v = *(const short8*)(A + arow * 128 + kk * 32 + quad * 8);
            afrag[kk] = v;
        }
    } else {
        const float* A = (const float*)Ain;
#pragma unroll
        for (int kk = 0; kk < 4; ++kk) {
            short8 v = {};
            if (ok) {
                const floatx4* p = (const floatx4*)(A + arow * 128 + kk * 32 + quad * 8);
                floatx4 fa = p[0], fb = p[1];
                v[0] = f2bf(fa.x); v[1] = f2bf(fa.y); v[2] = f2bf(fa.z); v[3] = f2bf(fa.w);
                v[4] = f2bf(fb.x); v[5] = f2bf(fb.y); v[6] = f2bf(fb.z); v[7] = f2bf(fb.w);
            }
            afrag[kk] = v;
        }
    }
    __syncthreads();

    floatx4 acc[8] = {};
#pragma unroll
    for (int n0 = 0; n0 < 8; ++n0) {
#pragma unroll
        for (int kk = 0; kk < 4; ++kk) {
            short8 bb = *(const short8*)&lds[(n0 * 16 + ln) * WT_PAD + kk * 32 + quad * 8];
            acc[n0] = __builtin_amdgcn_mfma_f32_16x16x32_bf16(afrag[kk], bb, acc[n0], 0, 0, 0);
        }
    }

    __syncthreads();  // done with Wt; reuse LDS for epilogue transpose
    unsigned short* st = &lds[wave * 16 * WT_PAD];
    float dv[4];
#pragma unroll
    for (int r = 0; r < 4; ++r) {
        int node = row_base + quad * 4 + r;
        dv[r] = (node < N_NODES) ? rsqrtf((float)(ctr[wave * 16 + quad * 4 + r] + 1)) : 0.f;
    }
#pragma unroll
    for (int n0 = 0; n0 < 8; ++n0)
#pragma unroll
        for (int r = 0; r < 4; ++r)
            st[(quad * 4 + r) * WT_PAD + n0 * 16 + ln] =
                (unsigned short)f2bf(acc[n0][r] * dv[r]);
    __syncthreads();

#pragma unroll
    for (int i = 0; i < 4; ++i) {
        int row = i * 4 + quad;
        int node = row_base + row;
        short8 v = *(const short8*)&st[row * WT_PAD + ln * 8];
        if (node < N_NODES) *(short8*)(g + node * 128 + ln * 8) = v;
    }
}

// -------- dispatch 4: standalone MFMA gemm (layer 2+3), dinv from global counts --------

__global__ __launch_bounds__(256) void gemm_mfma(const unsigned short* __restrict__ A,
                                                 const unsigned short* __restrict__ Wt,
                                                 const int* __restrict__ degs,
                                                 unsigned short* __restrict__ g) {
    __shared__ unsigned short lds[128 * WT_PAD];  // 34816 B; reused by epilogue
    int tid = threadIdx.x;
    int wave = tid >> 6, lane = tid & 63;
    int quad = lane >> 4, ln = lane & 15;

    {   // stage Wt (16384 shorts)
        int r = tid >> 1, h = tid & 1;
        const int4* src = (const int4*)(Wt + r * 128 + h * 64);
#pragma unroll
        for (int i = 0; i < 8; ++i)
            *(int4*)&lds[r * WT_PAD + h * 64 + i * 8] = src[i];
    }

    int row_base = blockIdx.x * 64 + wave * 16;
    int arow = row_base + ln;
    bool ok = arow < N_NODES;
    short8 afrag[4];
#pragma unroll
    for (int kk = 0; kk < 4; ++kk) {
        short8 v = {};
        if (ok) v = *(const short8*)(A + arow * 128 + kk * 32 + quad * 8);
        afrag[kk] = v;
    }
    __syncthreads();

    floatx4 acc[8] = {};
#pragma unroll
    for (int n0 = 0; n0 < 8; ++n0) {
#pragma unroll
        for (int kk = 0; kk < 4; ++kk) {
            short8 b = *(const short8*)&lds[(n0 * 16 + ln) * WT_PAD + kk * 32 + quad * 8];
            acc[n0] = __builtin_amdgcn_mfma_f32_16x16x32_bf16(afrag[kk], b, acc[n0], 0, 0, 0);
        }
    }

    __syncthreads();  // done with Wt; reuse LDS for epilogue transpose
    unsigned short* st = &lds[wave * 16 * WT_PAD];
    float dv[4];
#pragma unroll
    for (int r = 0; r < 4; ++r) {
        int node = row_base + quad * 4 + r;
        dv[r] = (node < N_NODES) ? rsqrtf((float)(degs[node] + 1)) : 0.f;
    }
#pragma unroll
    for (int n0 = 0; n0 < 8; ++n0)
#pragma unroll
        for (int r = 0; r < 4; ++r)
            st[(quad * 4 + r) * WT_PAD + n0 * 16 + ln] =
                (unsigned short)f2bf(acc[n0][r] * dv[r]);
    __syncthreads();

#pragma unroll
    for (int i = 0; i < 4; ++i) {
        int row = i * 4 + quad;
        int node = row_base + row;
        short8 v = *(const short8*)&st[row * WT_PAD + ln * 8];
        if (node < N_NODES) *(short8*)(g + node * 128 + ln * 8) = v;
    }
}

// -------- dispatches 3/5: aggregation, 16 lanes/node, 16-deep gather pipeline ----------
// Identical structure/numerics to the proven round-8 kernel; the inner loop is widened
// to 16 in-flight gathers (one chunk covers mean degree). Per-accumulator FP addition
// order is bitwise identical to two sequential 8-wide chunks.

#define UNPK_A(v) { a0 += bflo(v.x); a1 += bfhi(v.x); a2 += bflo(v.y); a3 += bfhi(v.y); \
                    a4 += bflo(v.z); a5 += bfhi(v.z); a6 += bflo(v.w); a7 += bfhi(v.w); }
#define UNPK_C(v) { c0 += bflo(v.x); c1 += bfhi(v.x); c2 += bflo(v.y); c3 += bfhi(v.y); \
                    c5 += bflo(v.z); c6 += bfhi(v.z); c7 += bflo(v.w); c8 += bfhi(v.w); }

template <int MODE>  // 0: bf16 out [N][128]; 1: fp32 split out (x1 | x2 by channel half)
__global__ __launch_bounds__(256) void aggregate_bf16(const unsigned short* __restrict__ g,
                                                      const int* __restrict__ degs,
                                                      const unsigned short* __restrict__ srcs,
                                                      const float* __restrict__ bias,
                                                      void* __restrict__ outp) {
    int n = blockIdx.x * 16 + (threadIdx.x >> 4);    // 3125*16 = 50000 exactly
    int c4 = threadIdx.x & 15;                       // uint4 index within the 256 B row
    const uint4* grow = (const uint4*)g;             // 16 uint4 per row
    uint4 u = grow[n * 16 + c4];                     // self-loop term
    float a0 = bflo(u.x), a1 = bfhi(u.x), a2 = bflo(u.y), a3 = bfhi(u.y);
    float a4 = bflo(u.z), a5 = bfhi(u.z), a6 = bflo(u.w), a7 = bfhi(u.w);
    float c0 = 0.f, c1 = 0.f, c2 = 0.f, c3 = 0.f, c5 = 0.f, c6 = 0.f, c7 = 0.f, c8 = 0.f;
    int deg = degs[n];
    int degc = deg > 64 ? 64 : deg;
    int beg = n << SLOT_LOG;
    int pend = beg + ((degc + 3) & ~3);              // pad slots hold DUMMY (zero row)
    int e = beg;
    for (; e + 16 <= pend; e += 16) {                // 16 gathers in flight
        ushort4 sa = *(const ushort4*)&srcs[e];
        ushort4 sb = *(const ushort4*)&srcs[e + 4];
        ushort4 sc = *(const ushort4*)&srcs[e + 8];
        ushort4 sd = *(const ushort4*)&srcs[e + 12];
        uint4 v0 = grow[sa.x * 16 + c4];
        uint4 v1 = grow[sa.y * 16 + c4];
        uint4 v2 = grow[sa.z * 16 + c4];
        uint4 v3 = grow[sa.w * 16 + c4];
        uint4 v4 = grow[sb.x * 16 + c4];
        uint4 v5 = grow[sb.y * 16 + c4];
        uint4 v6 = grow[sb.z * 16 + c4];
        uint4 v7 = grow[sb.w * 16 + c4];
        uint4 v8 = grow[sc.x * 16 + c4];
        uint4 v9 = grow[sc.y * 16 + c4];
        uint4 va = grow[sc.z * 16 + c4];
        uint4 vb = grow[sc.w * 16 + c4];
        uint4 vc = grow[sd.x * 16 + c4];
        uint4 vd = grow[sd.y * 16 + c4];
        uint4 ve = grow[sd.z * 16 + c4];
        uint4 vf = grow[sd.w * 16 + c4];
        UNPK_A(v0) UNPK_C(v1) UNPK_A(v2) UNPK_C(v3)
        UNPK_A(v4) UNPK_C(v5) UNPK_A(v6) UNPK_C(v7)
        UNPK_A(v8) UNPK_C(v9) UNPK_A(va) UNPK_C(vb)
        UNPK_A(vc) UNPK_C(vd) UNPK_A(ve) UNPK_C(vf)
    }
    if (e + 8 <= pend) {
        ushort4 sa = *(const ushort4*)&srcs[e];
        ushort4 sb = *(const ushort4*)&srcs[e + 4];
        uint4 v0 = grow[sa.x * 16 + c4];
        uint4 v1 = grow[sa.y * 16 + c4];
        uint4 v2 = grow[sa.z * 16 + c4];
        uint4 v3 = grow[sa.w * 16 + c4];
        uint4 v4 = grow[sb.x * 16 + c4];
        uint4 v5 = grow[sb.y * 16 + c4];
        uint4 v6 = grow[sb.z * 16 + c4];
        uint4 v7 = grow[sb.w * 16 + c4];
        UNPK_A(v0) UNPK_C(v1) UNPK_A(v2) UNPK_C(v3)
        UNPK_A(v4) UNPK_C(v5) UNPK_A(v6) UNPK_C(v7)
        e += 8;
    }
    if (e < pend) {  // exactly one 4-wide chunk remains (pend-beg is a multiple of 4)
        ushort4 sa = *(const ushort4*)&srcs[e];
        uint4 v0 = grow[sa.x * 16 + c4];
        uint4 v1 = grow[sa.y * 16 + c4];
        uint4 v2 = grow[sa.z * 16 + c4];
        uint4 v3 = grow[sa.w * 16 + c4];
        UNPK_A(v0) UNPK_C(v1) UNPK_A(v2) UNPK_C(v3)
    }
    a0 += c0; a1 += c1; a2 += c2; a3 += c3; a4 += c5; a5 += c6; a6 += c7; a7 += c8;
    float d = rsqrtf((float)(deg + 1));
    float4 bv0 = ((const float4*)bias)[c4 * 2];      // channels c4*8 .. c4*8+7
    float4 bv1 = ((const float4*)bias)[c4 * 2 + 1];
    float o0 = fmaxf(d * a0 + bv0.x, 0.f);
    float o1 = fmaxf(d * a1 + bv0.y, 0.f);
    float o2 = fmaxf(d * a2 + bv0.z, 0.f);
    float o3 = fmaxf(d * a3 + bv0.w, 0.f);
    float o4 = fmaxf(d * a4 + bv1.x, 0.f);
    float o5 = fmaxf(d * a5 + bv1.y, 0.f);
    float o6 = fmaxf(d * a6 + bv1.z, 0.f);
    float o7 = fmaxf(d * a7 + bv1.w, 0.f);
    if (MODE == 0) {
        uint4 w;
        w.x = ((unsigned)(unsigned short)f2bf(o0)) | (((unsigned)(unsigned short)f2bf(o1)) << 16);
        w.y = ((unsigned)(unsigned short)f2bf(o2)) | (((unsigned)(unsigned short)f2bf(o3)) << 16);
        w.z = ((unsigned)(unsigned short)f2bf(o4)) | (((unsigned)(unsigned short)f2bf(o5)) << 16);
        w.w = ((unsigned)(unsigned short)f2bf(o6)) | (((unsigned)(unsigned short)f2bf(o7)) << 16);
        ((uint4*)outp)[n * 16 + c4] = w;             // hidden is reused by gemm2: keep cached
    } else {
        // half 0 == x1 exactly; half 1 == x2 exactly (64 ch each, fp32)
        int hh = c4 >> 3, cc = c4 & 7;
        float* out = (float*)outp + (size_t)hh * N_NODES * 64;
        floatx4* o = (floatx4*)out + n * 16 + cc * 2;
        floatx4 w0; w0.x = o0; w0.y = o1; w0.z = o2; w0.w = o3;
        floatx4 w1; w1.x = o4; w1.y = o5; w1.z = o6; w1.w = o7;
        __builtin_nontemporal_store(w0, o);
        __builtin_nontemporal_store(w1, o + 1);
    }
}

// ---------------- launch (5 dispatches) ----------------

extern "C" void kernel_launch(void* const* d_in, const int* in_sizes, int n_in,
                              void* d_out, int out_size, void* d_ws, size_t ws_size,
                              hipStream_t stream) {
    const float* x  = (const float*)d_in[0];
    const int*   ei = (const int*)d_in[1];   // [2, E] int32
    const float* W1 = (const float*)d_in[2];
    const float* b1 = (const float*)d_in[3];
    const float* W2 = (const float*)d_in[4];
    const float* b2 = (const float*)d_in[5];
    const float* W3 = (const float*)d_in[6];
    const float* b3 = (const float*)d_in[7];
    float* out = (float*)d_out;

    // Workspace layout. bd2 (17.17 MB, dead after csr_gemm1) overlays hidden (written
    // first by agg1). Total 37,248,128 B < 38,490,112 previously proven.
    char* w = (char*)d_ws;
    int*            counts     = (int*)(w + 0);                   // 200,000 B (true degree)
    int*            cnt2d      = (int*)(w + 200704);              // 613,088 B (196*782 ints)
    unsigned short* Wt1        = (unsigned short*)(w + 815104);   // 32,768 B
    unsigned short* Wt23       = (unsigned short*)(w + 847872);   // 32,768 B
    float*          b23        = (float*)(w + 880640);            // 512 B
    unsigned short* sorted_src = (unsigned short*)(w + 881152);   // 6,400,000 B
    unsigned short* g1         = (unsigned short*)(w + 7281152);  // 12,800,256 B (+dummy row)
    unsigned*       bd2        = (unsigned*)(w + 20081664);       // 17,166,464 B (196*782*28*4)
    unsigned short* hidden     = (unsigned short*)(w + 20081664); // 12,800,000 B (overlays bd2)

    partition_prep<<<PART_BLOCKS, 256, 0, stream>>>(ei, W1, W2, W3, b2, b3, Wt1, Wt23, b23,
                                                    cnt2d, bd2,
                                                    (unsigned int*)(g1 + N_NODES * 128));

    // layer 1 (fused CSR + gemm): g1 = bf16(dinv * (x @ W1)); then hidden via aggregate
    csr_gemm<false><<<NB2, 256, 0, stream>>>(bd2, cnt2d, x, Wt1, counts, sorted_src, g1);
    aggregate_bf16<0><<<AGG_BLKS, 256, 0, stream>>>(g1, counts, sorted_src, b1, hidden);

    // layers 2+3 fused: g1 = bf16(dinv * (hidden @ [W2|W3])); out = relu split
    gemm_mfma<<<NB2, 256, 0, stream>>>(hidden, Wt23, counts, g1);
    aggregate_bf16<1><<<AGG_BLKS, 256, 0, stream>>>(g1, counts, sorted_src, b23, out);
}